// Round 1
// baseline (400.283 us; speedup 1.0000x reference)
//
#include <hip/hip_runtime.h>
#include <hip/hip_bf16.h>
#include <math.h>

#define DM 768
#define HEADS 12
#define HD 64
#define BQ 2
#define TQ 2048
#define TK 4096

typedef __attribute__((ext_vector_type(8))) short bf16x8;   // 8 bf16 (4 VGPRs) MFMA frag
typedef __attribute__((ext_vector_type(4))) float f32x4;    // MFMA accum
typedef __attribute__((ext_vector_type(4))) short short4v;  // 8B vector

__device__ inline short f2bf(float f) {
    union { float f; unsigned u; } a; a.f = f;
    unsigned r = a.u + 0x7fff + ((a.u >> 16) & 1);  // RNE
    return (short)(r >> 16);
}

// ---------------------------------------------------------------------------
// RoPE tables. Reference: emb = concat([sin(t*invf), cos(t*invf)]), then
// sin_u[j] = emb[2j], cos_u[j] = emb[2j+1]  (j in [0,32)).
//   j<16 : sin_u = sin(t*invf[2j]),   cos_u = sin(t*invf[2j+1])
//   j>=16: sin_u = cos(t*invf[2j-32]), cos_u = cos(t*invf[2j-31])
// invf[i] = 10000^(-2i/64). Computed in fp64 to match the np float64 ref.
// ---------------------------------------------------------------------------
__global__ void rope_tables(float* sin_u, float* cos_u) {
    int idx = blockIdx.x * 256 + threadIdx.x;
    if (idx >= TK * 32) return;
    int t = idx >> 5, j = idx & 31;
    double su, cu;
    if (j < 16) {
        su = sin((double)t * pow(10000.0, -(double)(2 * (2 * j)) / 64.0));
        cu = sin((double)t * pow(10000.0, -(double)(2 * (2 * j + 1)) / 64.0));
    } else {
        su = cos((double)t * pow(10000.0, -(double)(2 * (2 * j - 32)) / 64.0));
        cu = cos((double)t * pow(10000.0, -(double)(2 * (2 * j - 31)) / 64.0));
    }
    sin_u[idx] = (float)su;
    cos_u[idx] = (float)cu;
}

// ---------------------------------------------------------------------------
// GEMM: Y[M x 768] = X[M x 768] @ W^T[768 x 768] + bias, fp32 out.
// X fp32 or bf16 (BF16IN). 128x128 tile, 4 waves (2x2 of 64x64), BK=32.
// LDS row stride padded 32->40 shorts (80B): bank-start 20r mod 32 -> 2-way
// (free) instead of 8-way.
// MFMA 16x16x32 bf16 layouts: A row=l&15,k=(l>>4)*8+j ; B col=l&15, same k;
// D row=(l>>4)*4+r, col=l&15  [guide-verified].
// ---------------------------------------------------------------------------
template<int BF16IN>
__global__ __launch_bounds__(256) void gemm_xwT(const void* Xv, const float* W,
                                                const float* bias, float* Y, int M) {
    __shared__ short Alds[128 * 40];
    __shared__ short Blds[128 * 40];
    const int tid = threadIdx.x;
    const int lane = tid & 63, wid = tid >> 6;
    const int wr = wid >> 1, wc = wid & 1;
    const int l4 = lane >> 4, l15 = lane & 15;
    const int bm = blockIdx.x * 128, bn = blockIdx.y * 128;
    const float* Xf = (const float*)Xv;
    const short* Xh = (const short*)Xv;

    f32x4 acc[4][4] = {};

    for (int k0 = 0; k0 < DM; k0 += 32) {
        __syncthreads();
#pragma unroll
        for (int p = 0; p < 4; ++p) {
            int c = p * 256 + tid;          // 0..1023
            int row = c >> 3, kq = (c & 7) * 4;
            short4v s;
            if (BF16IN) {
                s = *reinterpret_cast<const short4v*>(&Xh[(size_t)(bm + row) * DM + k0 + kq]);
            } else {
                float4 f = *reinterpret_cast<const float4*>(&Xf[(size_t)(bm + row) * DM + k0 + kq]);
                s.x = f2bf(f.x); s.y = f2bf(f.y); s.z = f2bf(f.z); s.w = f2bf(f.w);
            }
            *reinterpret_cast<short4v*>(&Alds[row * 40 + kq]) = s;
            float4 g = *reinterpret_cast<const float4*>(&W[(size_t)(bn + row) * DM + k0 + kq]);
            short4v t4;
            t4.x = f2bf(g.x); t4.y = f2bf(g.y); t4.z = f2bf(g.z); t4.w = f2bf(g.w);
            *reinterpret_cast<short4v*>(&Blds[row * 40 + kq]) = t4;
        }
        __syncthreads();
        bf16x8 af[4], bfr[4];
#pragma unroll
        for (int i = 0; i < 4; ++i)
            af[i] = *reinterpret_cast<const bf16x8*>(&Alds[(wr * 64 + i * 16 + l15) * 40 + l4 * 8]);
#pragma unroll
        for (int j = 0; j < 4; ++j)
            bfr[j] = *reinterpret_cast<const bf16x8*>(&Blds[(wc * 64 + j * 16 + l15) * 40 + l4 * 8]);
#pragma unroll
        for (int i = 0; i < 4; ++i)
#pragma unroll
            for (int j = 0; j < 4; ++j)
                acc[i][j] = __builtin_amdgcn_mfma_f32_16x16x32_bf16(af[i], bfr[j], acc[i][j], 0, 0, 0);
    }

#pragma unroll
    for (int i = 0; i < 4; ++i) {
        int m = bm + wr * 64 + i * 16 + l4 * 4;
#pragma unroll
        for (int j = 0; j < 4; ++j) {
            int n = bn + wc * 64 + j * 16 + l15;
            float bb = bias[n];
#pragma unroll
            for (int r = 0; r < 4; ++r)
                Y[(size_t)(m + r) * DM + n] = acc[i][j][r] + bb;
        }
    }
}

// ---------------------------------------------------------------------------
// RoPE + transpose to head-major bf16: Y[b*T+t][h*64+d] -> out[(b*H+h)*T+t][d]
// out[j] = x1*cos_u - x2*sin_u ; out[j+32] = x1*sin_u + x2*cos_u, x1=x[2j],x2=x[2j+1]
// ---------------------------------------------------------------------------
__global__ void rope_trans(const float* __restrict__ Y, const float* __restrict__ sin_u,
                           const float* __restrict__ cos_u, short* __restrict__ outHT, int T) {
    int idx = blockIdx.x * 256 + threadIdx.x;
    if (idx >= BQ * T * HEADS * 32) return;
    int j = idx & 31;
    int tmp = idx >> 5;
    int h = tmp % HEADS;
    int row = tmp / HEADS;          // b*T + t
    int b = row / T, t = row - b * T;
    float2 x = *reinterpret_cast<const float2*>(&Y[(size_t)row * DM + h * 64 + 2 * j]);
    float su = sin_u[t * 32 + j], cu = cos_u[t * 32 + j];
    size_t base = ((size_t)(b * HEADS + h) * T + t) * 64;
    outHT[base + j]      = f2bf(x.x * cu - x.y * su);
    outHT[base + 32 + j] = f2bf(x.x * su + x.y * cu);
}

// ---------------------------------------------------------------------------
// V transpose: Y[b*TK+t][h*64+d] -> vt[(b*H+h)*64+d][t]  (bf16), LDS-tiled.
// ---------------------------------------------------------------------------
__global__ __launch_bounds__(256) void v_trans(const float* __restrict__ Y, short* __restrict__ vt) {
    __shared__ float tile[64][65];
    int tb = blockIdx.x, h = blockIdx.y, b = blockIdx.z;
    int tid = threadIdx.x;
#pragma unroll
    for (int p = 0; p < 4; ++p) {
        int c = p * 256 + tid;        // 0..1023
        int tr = c >> 4, d4 = (c & 15) * 4;
        float4 f = *reinterpret_cast<const float4*>(&Y[(size_t)(b * TK + tb * 64 + tr) * DM + h * 64 + d4]);
        tile[tr][d4] = f.x; tile[tr][d4 + 1] = f.y; tile[tr][d4 + 2] = f.z; tile[tr][d4 + 3] = f.w;
    }
    __syncthreads();
#pragma unroll
    for (int p = 0; p < 4; ++p) {
        int c = p * 256 + tid;
        int d = c >> 4, t4 = (c & 15) * 4;
        short4v s;
        s.x = f2bf(tile[t4 + 0][d]); s.y = f2bf(tile[t4 + 1][d]);
        s.z = f2bf(tile[t4 + 2][d]); s.w = f2bf(tile[t4 + 3][d]);
        *reinterpret_cast<short4v*>(&vt[((size_t)(b * HEADS + h) * 64 + d) * TK + tb * 64 + t4]) = s;
    }
}

// ---------------------------------------------------------------------------
// Flash attention: per (q-tile 64, h, b). 4 waves x 16 q-rows. K-tiles of 64.
// qh: [b][h][t][d] bf16 ; kh: [b][h][t][d] bf16 ; vt: [b][h][d][t] bf16.
// Online softmax with 16-lane shfl_xor reductions; P repacked via LDS.
// ---------------------------------------------------------------------------
__global__ __launch_bounds__(256) void attn(const short* __restrict__ qh, const short* __restrict__ kh,
                                            const short* __restrict__ vt, short* __restrict__ outA) {
    __shared__ short Klds[64 * 72];   // [key][d], pad 64->72 (2-way free)
    __shared__ short Vlds[64 * 72];   // [d][key]
    __shared__ short Plds[64 * 72];   // [qrow][key]
    int qt = blockIdx.x, h = blockIdx.y, b = blockIdx.z;
    int tid = threadIdx.x, lane = tid & 63, w = tid >> 6;
    int l4 = lane >> 4, l15 = lane & 15;
    size_t bh = (size_t)(b * HEADS + h);

    bf16x8 qf[2];
    {
        size_t qbase = (bh * TQ + (size_t)qt * 64 + w * 16 + l15) * 64;
        qf[0] = *reinterpret_cast<const bf16x8*>(&qh[qbase + l4 * 8]);
        qf[1] = *reinterpret_cast<const bf16x8*>(&qh[qbase + 32 + l4 * 8]);
    }

    f32x4 oacc[4] = {};
    float m[4], lsum[4];
#pragma unroll
    for (int r = 0; r < 4; ++r) { m[r] = -INFINITY; lsum[r] = 0.f; }

    const short* kbase = &kh[bh * TK * 64];
    const short* vbase = &vt[bh * 64 * TK];

    for (int kt = 0; kt < TK / 64; ++kt) {
        __syncthreads();   // prev PV done before restaging K/V
#pragma unroll
        for (int p = 0; p < 2; ++p) {
            int c = p * 256 + tid;      // 0..511
            int row = c >> 3, cg = (c & 7) * 8;
            *reinterpret_cast<bf16x8*>(&Klds[row * 72 + cg]) =
                *reinterpret_cast<const bf16x8*>(&kbase[((size_t)kt * 64 + row) * 64 + cg]);
            *reinterpret_cast<bf16x8*>(&Vlds[row * 72 + cg]) =
                *reinterpret_cast<const bf16x8*>(&vbase[(size_t)row * TK + kt * 64 + cg]);
        }
        __syncthreads();

        // S = Q K^T  (16 q-rows x 64 keys per wave)
        f32x4 sacc[4] = {};
#pragma unroll
        for (int j = 0; j < 4; ++j)
#pragma unroll
            for (int kk = 0; kk < 2; ++kk) {
                bf16x8 bfr = *reinterpret_cast<const bf16x8*>(&Klds[(j * 16 + l15) * 72 + kk * 32 + l4 * 8]);
                sacc[j] = __builtin_amdgcn_mfma_f32_16x16x32_bf16(qf[kk], bfr, sacc[j], 0, 0, 0);
            }

        // online softmax
        float p[4][4];
#pragma unroll
        for (int r = 0; r < 4; ++r) {
            float mx = -INFINITY;
#pragma unroll
            for (int j = 0; j < 4; ++j) mx = fmaxf(mx, sacc[j][r]);
            mx *= 0.125f;
            mx = fmaxf(mx, __shfl_xor(mx, 1));
            mx = fmaxf(mx, __shfl_xor(mx, 2));
            mx = fmaxf(mx, __shfl_xor(mx, 4));
            mx = fmaxf(mx, __shfl_xor(mx, 8));
            float mnew = fmaxf(m[r], mx);
            float alpha = expf(m[r] - mnew);
            float rs = 0.f;
#pragma unroll
            for (int j = 0; j < 4; ++j) {
                float pv = expf(sacc[j][r] * 0.125f - mnew);
                p[j][r] = pv;
                rs += pv;
            }
            rs += __shfl_xor(rs, 1); rs += __shfl_xor(rs, 2);
            rs += __shfl_xor(rs, 4); rs += __shfl_xor(rs, 8);
            lsum[r] = lsum[r] * alpha + rs;
            m[r] = mnew;
#pragma unroll
            for (int dj = 0; dj < 4; ++dj) oacc[dj][r] *= alpha;
        }

        // repack P -> LDS (bf16)
#pragma unroll
        for (int j = 0; j < 4; ++j)
#pragma unroll
            for (int r = 0; r < 4; ++r)
                Plds[(w * 16 + l4 * 4 + r) * 72 + j * 16 + l15] = f2bf(p[j][r]);
        __syncthreads();

        // O += P V
        bf16x8 aP[2];
        aP[0] = *reinterpret_cast<const bf16x8*>(&Plds[(w * 16 + l15) * 72 + l4 * 8]);
        aP[1] = *reinterpret_cast<const bf16x8*>(&Plds[(w * 16 + l15) * 72 + 32 + l4 * 8]);
#pragma unroll
        for (int dj = 0; dj < 4; ++dj)
#pragma unroll
            for (int kk = 0; kk < 2; ++kk) {
                bf16x8 bV = *reinterpret_cast<const bf16x8*>(&Vlds[(dj * 16 + l15) * 72 + kk * 32 + l4 * 8]);
                oacc[dj] = __builtin_amdgcn_mfma_f32_16x16x32_bf16(aP[kk], bV, oacc[dj], 0, 0, 0);
            }
    }

    // normalize + write [b][t][h*64+d] bf16 (token-major for final GEMM)
#pragma unroll
    for (int dj = 0; dj < 4; ++dj)
#pragma unroll
        for (int r = 0; r < 4; ++r) {
            int qrow = qt * 64 + w * 16 + l4 * 4 + r;
            int d = dj * 16 + l15;
            float o = oacc[dj][r] / lsum[r];
            outA[((size_t)(b * TQ + qrow) * HEADS + h) * 64 + d] = f2bf(o);
        }
}

// ---------------------------------------------------------------------------
extern "C" void kernel_launch(void* const* d_in, const int* in_sizes, int n_in,
                              void* d_out, int out_size, void* d_ws, size_t ws_size,
                              hipStream_t stream) {
    const float* query = (const float*)d_in[0];
    const float* key_  = (const float*)d_in[1];
    const float* value = (const float*)d_in[2];
    const float* Wq = (const float*)d_in[3];
    const float* bq = (const float*)d_in[4];
    const float* Wk = (const float*)d_in[5];
    const float* bk = (const float*)d_in[6];
    const float* Wv = (const float*)d_in[7];
    const float* bv = (const float*)d_in[8];
    const float* Wo = (const float*)d_in[9];
    const float* bo = (const float*)d_in[10];
    float* out = (float*)d_out;

    char* ws = (char*)d_ws;
    float* sin_u = (float*)(ws + 0);            //   524,288 B
    float* cos_u = (float*)(ws + 524288);       //   524,288 B
    short* qh    = (short*)(ws + 1048576);      // 6,291,456 B
    short* kh    = (short*)(ws + 7340032);      // 12,582,912 B
    short* vt    = (short*)(ws + 19922944);     // 12,582,912 B
    short* attnO = (short*)(ws + 32505856);     // 6,291,456 B
    float* Y     = (float*)(ws + 38797312);     // 25,165,824 B (end ~64 MB)

    dim3 blk(256);

    rope_tables<<<(TK * 32 + 255) / 256, blk, 0, stream>>>(sin_u, cos_u);

    // Q
    gemm_xwT<0><<<dim3(BQ * TQ / 128, DM / 128), blk, 0, stream>>>(query, Wq, bq, Y, BQ * TQ);
    rope_trans<<<(BQ * TQ * HEADS * 32 + 255) / 256, blk, 0, stream>>>(Y, sin_u, cos_u, qh, TQ);
    // K
    gemm_xwT<0><<<dim3(BQ * TK / 128, DM / 128), blk, 0, stream>>>(key_, Wk, bk, Y, BQ * TK);
    rope_trans<<<(BQ * TK * HEADS * 32 + 255) / 256, blk, 0, stream>>>(Y, sin_u, cos_u, kh, TK);
    // V
    gemm_xwT<0><<<dim3(BQ * TK / 128, DM / 128), blk, 0, stream>>>(value, Wv, bv, Y, BQ * TK);
    v_trans<<<dim3(TK / 64, HEADS, BQ), blk, 0, stream>>>(Y, vt);
    // attention
    attn<<<dim3(TQ / 64, HEADS, BQ), blk, 0, stream>>>(qh, kh, vt, attnO);
    // output projection (bf16 input)
    gemm_xwT<1><<<dim3(BQ * TQ / 128, DM / 128), blk, 0, stream>>>(attnO, Wo, bo, out, BQ * TQ);
}

// Round 2
// 312.983 us; speedup vs baseline: 1.2789x; 1.2789x over previous
//
#include <hip/hip_runtime.h>
#include <hip/hip_bf16.h>
#include <math.h>

#define DM 768
#define HEADS 12
#define BQ 2
#define TQ 2048
#define TK 4096

typedef __attribute__((ext_vector_type(8))) short bf16x8;   // 8 bf16 (4 VGPRs) MFMA frag
typedef __attribute__((ext_vector_type(4))) float f32x4;    // 16x16 MFMA accum
typedef __attribute__((ext_vector_type(16))) float f32x16;  // 32x32 MFMA accum
typedef __attribute__((ext_vector_type(4))) short short4v;  // 8B vector

__device__ inline short f2bf(float f) {
    union { float f; unsigned u; } a; a.f = f;
    unsigned r = a.u + 0x7fff + ((a.u >> 16) & 1);  // RNE
    return (short)(r >> 16);
}

// packed 2x f32 -> 1x u32 (2 bf16, lo = first arg); compiles to v_cvt_pk_bf16_f32
__device__ inline unsigned pk2bf(float a, float b) {
    union { __hip_bfloat162 h; unsigned u; } c;
    c.h = __float22bfloat162_rn(make_float2(a, b));
    return c.u;
}

// ---------------------------------------------------------------------------
// RoPE tables (fp64, matches np float64 ref). See R0 derivation.
// ---------------------------------------------------------------------------
__global__ void rope_tables(float* sin_u, float* cos_u) {
    int idx = blockIdx.x * 256 + threadIdx.x;
    if (idx >= TK * 32) return;
    int t = idx >> 5, j = idx & 31;
    double su, cu;
    if (j < 16) {
        su = sin((double)t * pow(10000.0, -(double)(2 * (2 * j)) / 64.0));
        cu = sin((double)t * pow(10000.0, -(double)(2 * (2 * j + 1)) / 64.0));
    } else {
        su = cos((double)t * pow(10000.0, -(double)(2 * (2 * j - 32)) / 64.0));
        cu = cos((double)t * pow(10000.0, -(double)(2 * (2 * j - 31)) / 64.0));
    }
    sin_u[idx] = (float)su;
    cos_u[idx] = (float)cu;
}

// ---------------------------------------------------------------------------
// GEMM: Y[M x 768] = X[M x 768] @ W^T + bias (fp32 out). Unchanged from R0.
// ---------------------------------------------------------------------------
template<int BF16IN>
__global__ __launch_bounds__(256) void gemm_xwT(const void* Xv, const float* W,
                                                const float* bias, float* Y, int M) {
    __shared__ short Alds[128 * 40];
    __shared__ short Blds[128 * 40];
    const int tid = threadIdx.x;
    const int lane = tid & 63, wid = tid >> 6;
    const int wr = wid >> 1, wc = wid & 1;
    const int l4 = lane >> 4, l15 = lane & 15;
    const int bm = blockIdx.x * 128, bn = blockIdx.y * 128;
    const float* Xf = (const float*)Xv;
    const short* Xh = (const short*)Xv;

    f32x4 acc[4][4] = {};

    for (int k0 = 0; k0 < DM; k0 += 32) {
        __syncthreads();
#pragma unroll
        for (int p = 0; p < 4; ++p) {
            int c = p * 256 + tid;
            int row = c >> 3, kq = (c & 7) * 4;
            short4v s;
            if (BF16IN) {
                s = *reinterpret_cast<const short4v*>(&Xh[(size_t)(bm + row) * DM + k0 + kq]);
            } else {
                float4 f = *reinterpret_cast<const float4*>(&Xf[(size_t)(bm + row) * DM + k0 + kq]);
                s.x = f2bf(f.x); s.y = f2bf(f.y); s.z = f2bf(f.z); s.w = f2bf(f.w);
            }
            *reinterpret_cast<short4v*>(&Alds[row * 40 + kq]) = s;
            float4 g = *reinterpret_cast<const float4*>(&W[(size_t)(bn + row) * DM + k0 + kq]);
            short4v t4;
            t4.x = f2bf(g.x); t4.y = f2bf(g.y); t4.z = f2bf(g.z); t4.w = f2bf(g.w);
            *reinterpret_cast<short4v*>(&Blds[row * 40 + kq]) = t4;
        }
        __syncthreads();
        bf16x8 af[4], bfr[4];
#pragma unroll
        for (int i = 0; i < 4; ++i)
            af[i] = *reinterpret_cast<const bf16x8*>(&Alds[(wr * 64 + i * 16 + l15) * 40 + l4 * 8]);
#pragma unroll
        for (int j = 0; j < 4; ++j)
            bfr[j] = *reinterpret_cast<const bf16x8*>(&Blds[(wc * 64 + j * 16 + l15) * 40 + l4 * 8]);
#pragma unroll
        for (int i = 0; i < 4; ++i)
#pragma unroll
            for (int j = 0; j < 4; ++j)
                acc[i][j] = __builtin_amdgcn_mfma_f32_16x16x32_bf16(af[i], bfr[j], acc[i][j], 0, 0, 0);
    }

#pragma unroll
    for (int i = 0; i < 4; ++i) {
        int m = bm + wr * 64 + i * 16 + l4 * 4;
#pragma unroll
        for (int j = 0; j < 4; ++j) {
            int n = bn + wc * 64 + j * 16 + l15;
            float bb = bias[n];
#pragma unroll
            for (int r = 0; r < 4; ++r)
                Y[(size_t)(m + r) * DM + n] = acc[i][j][r] + bb;
        }
    }
}

// ---------------------------------------------------------------------------
// RoPE + transpose to head-major bf16, with output scale (Q gets 0.125*log2e
// folded in so attention softmax runs in exp2 domain; K gets 1.0).
// ---------------------------------------------------------------------------
__global__ void rope_trans(const float* __restrict__ Y, const float* __restrict__ sin_u,
                           const float* __restrict__ cos_u, short* __restrict__ outHT,
                           int T, float scale) {
    int idx = blockIdx.x * 256 + threadIdx.x;
    if (idx >= BQ * T * HEADS * 32) return;
    int j = idx & 31;
    int tmp = idx >> 5;
    int h = tmp % HEADS;
    int row = tmp / HEADS;          // b*T + t
    int b = row / T, t = row - b * T;
    float2 x = *reinterpret_cast<const float2*>(&Y[(size_t)row * DM + h * 64 + 2 * j]);
    float su = sin_u[t * 32 + j], cu = cos_u[t * 32 + j];
    size_t base = ((size_t)(b * HEADS + h) * T + t) * 64;
    outHT[base + j]      = f2bf((x.x * cu - x.y * su) * scale);
    outHT[base + 32 + j] = f2bf((x.x * su + x.y * cu) * scale);
}

// ---------------------------------------------------------------------------
// V transpose: Y[b*TK+t][h*64+d] -> vt[(b*H+h)*64+d][t]  (bf16). Unchanged.
// ---------------------------------------------------------------------------
__global__ __launch_bounds__(256) void v_trans(const float* __restrict__ Y, short* __restrict__ vt) {
    __shared__ float tile[64][65];
    int tb = blockIdx.x, h = blockIdx.y, b = blockIdx.z;
    int tid = threadIdx.x;
#pragma unroll
    for (int p = 0; p < 4; ++p) {
        int c = p * 256 + tid;
        int tr = c >> 4, d4 = (c & 15) * 4;
        float4 f = *reinterpret_cast<const float4*>(&Y[(size_t)(b * TK + tb * 64 + tr) * DM + h * 64 + d4]);
        tile[tr][d4] = f.x; tile[tr][d4 + 1] = f.y; tile[tr][d4 + 2] = f.z; tile[tr][d4 + 3] = f.w;
    }
    __syncthreads();
#pragma unroll
    for (int p = 0; p < 4; ++p) {
        int c = p * 256 + tid;
        int d = c >> 4, t4 = (c & 15) * 4;
        short4v s;
        s.x = f2bf(tile[t4 + 0][d]); s.y = f2bf(tile[t4 + 1][d]);
        s.z = f2bf(tile[t4 + 2][d]); s.w = f2bf(tile[t4 + 3][d]);
        *reinterpret_cast<short4v*>(&vt[((size_t)(b * HEADS + h) * 64 + d) * TK + tb * 64 + t4]) = s;
    }
}

// ---------------------------------------------------------------------------
// Flash attention, m214-style swapped-operand structure.
// Block = 4 waves x 32 q-rows = 128 q-rows. K-tiles of 64, double-buffered LDS
// (XOR-swizzled rows, byte ^= (row&7)<<4), 1 barrier/tile, prefetch-to-regs.
//
// QK^T (swapped): St[key,q] = mfma(A=K[key,d], B=Q^T[d,q])
//   -> D: col = lane&31 = q, row = crow(r,hi) = (r&3)+8*(r>>2)+4*hi = key.
//   Each lane owns 32 S-values of ITS q-row (keys crow over 2 key-tiles);
//   partner lane (lane^32) holds the complementary keys.
// Softmax fully in-register, exp2 domain (scale folded into Q).
// P->A-frag redistribution: per ks, quads (base,base+4); cvt_pk pairs, 2x
//   shfl_xor(32); lane keeps own-hi quad words, receives the others.
// PV (swapped): O^T[d,q] = mfma(A=V^T[d,key] (from vt), B=P^T[key,q]=pa)
//   -> D col = lane&31 = q again: alpha/lsum stay lane-local.
// ---------------------------------------------------------------------------
__global__ __launch_bounds__(256) void attn(const short* __restrict__ qh,
                                            const short* __restrict__ kh,
                                            const short* __restrict__ vt,
                                            short* __restrict__ outA) {
    __shared__ short Ks[2][64 * 64];
    __shared__ short Vs[2][64 * 64];
    const int qt = blockIdx.x, h = blockIdx.y, b = blockIdx.z;
    const int tid = threadIdx.x, lane = tid & 63, w = tid >> 6;
    const int l31 = lane & 31, hi = lane >> 5;
    const size_t bh = (size_t)(b * HEADS + h);
    const short* kbase = kh + bh * TK * 64;
    const short* vbase = vt + bh * (size_t)64 * TK;

    // swizzled LDS short-index for (row, byte-offset-within-128B-row)
#define SWZ(row, bo) ((row) * 64 + ((((bo)) ^ (((row) & 7) << 4)) >> 1))
#define KGLB(c, t_) (kbase + ((size_t)(t_) * 64 + ((c) >> 3)) * 64 + ((c) & 7) * 8)
#define VGLB(c, t_) (vbase + (size_t)((c) >> 3) * TK + (t_) * 64 + ((c) & 7) * 8)

    // Q fragments in registers (pre-scaled by 0.125*log2e)
    bf16x8 qf[4];
    {
        const short* qrow = qh + (bh * TQ + (size_t)qt * 128 + w * 32 + l31) * 64 + hi * 8;
#pragma unroll
        for (int d0 = 0; d0 < 4; ++d0)
            qf[d0] = *reinterpret_cast<const bf16x8*>(qrow + d0 * 16);
    }

    f32x16 oacc[2] = {};
    float m = -INFINITY, lsum = 0.f;

    const int c0 = tid, c1 = tid + 256;   // 2x 16B chunks each for K and V

    // prologue: stage tile 0
    {
        bf16x8 k0 = *reinterpret_cast<const bf16x8*>(KGLB(c0, 0));
        bf16x8 k1 = *reinterpret_cast<const bf16x8*>(KGLB(c1, 0));
        bf16x8 v0 = *reinterpret_cast<const bf16x8*>(VGLB(c0, 0));
        bf16x8 v1 = *reinterpret_cast<const bf16x8*>(VGLB(c1, 0));
        *reinterpret_cast<bf16x8*>(&Ks[0][SWZ(c0 >> 3, (c0 & 7) * 16)]) = k0;
        *reinterpret_cast<bf16x8*>(&Ks[0][SWZ(c1 >> 3, (c1 & 7) * 16)]) = k1;
        *reinterpret_cast<bf16x8*>(&Vs[0][SWZ(c0 >> 3, (c0 & 7) * 16)]) = v0;
        *reinterpret_cast<bf16x8*>(&Vs[0][SWZ(c1 >> 3, (c1 & 7) * 16)]) = v1;
    }
    __syncthreads();

    int cur = 0;
    for (int kt = 0; kt < TK / 64; ++kt) {
        const bool pre = (kt + 1 < TK / 64);
        bf16x8 sk0, sk1, sv0, sv1;
        if (pre) {   // issue next-tile loads early; latency hides under QK^T+softmax
            sk0 = *reinterpret_cast<const bf16x8*>(KGLB(c0, kt + 1));
            sk1 = *reinterpret_cast<const bf16x8*>(KGLB(c1, kt + 1));
            sv0 = *reinterpret_cast<const bf16x8*>(VGLB(c0, kt + 1));
            sv1 = *reinterpret_cast<const bf16x8*>(VGLB(c1, kt + 1));
        }

        // ---- QK^T ----
        f32x16 sacc[2] = {};
#pragma unroll
        for (int t2 = 0; t2 < 2; ++t2) {
            int row = t2 * 32 + l31;
#pragma unroll
            for (int d0 = 0; d0 < 4; ++d0) {
                bf16x8 kf = *reinterpret_cast<const bf16x8*>(&Ks[cur][SWZ(row, d0 * 32 + hi * 16)]);
                sacc[t2] = __builtin_amdgcn_mfma_f32_32x32x16_bf16(kf, qf[d0], sacc[t2], 0, 0, 0);
            }
        }

        // ---- online softmax (exp2 domain), per-lane row q = l31 ----
        float pmax = sacc[0][0];
#pragma unroll
        for (int i = 1; i < 16; ++i) pmax = fmaxf(pmax, sacc[0][i]);
#pragma unroll
        for (int i = 0; i < 16; ++i) pmax = fmaxf(pmax, sacc[1][i]);
        pmax = fmaxf(pmax, __shfl_xor(pmax, 32));
        if (!__all(pmax <= m + 8.f)) {      // T13 defer-max
            float mnew = fmaxf(m, pmax);
            float alpha = exp2f(m - mnew);
            lsum *= alpha;
#pragma unroll
            for (int t2 = 0; t2 < 2; ++t2)
#pragma unroll
                for (int i = 0; i < 16; ++i) oacc[t2][i] *= alpha;
            m = mnew;
        }
        float rs = 0.f;
#pragma unroll
        for (int t2 = 0; t2 < 2; ++t2)
#pragma unroll
            for (int i = 0; i < 16; ++i) {
                float e = exp2f(sacc[t2][i] - m);
                sacc[t2][i] = e;            // reuse sacc regs as P
                rs += e;
            }
        rs += __shfl_xor(rs, 32);
        lsum += rs;

        // ---- P -> PV fragments (cvt_pk + shfl_xor(32) redistribution) ----
#define PP(idx) (sacc[(idx) >> 4][(idx) & 15])
        bf16x8 pa[4];
#pragma unroll
        for (int ks = 0; ks < 4; ++ks) {
            const int base = (ks >> 1) * 16 + (ks & 1) * 8;
            unsigned u0 = pk2bf(PP(base + 0), PP(base + 1));
            unsigned u1 = pk2bf(PP(base + 2), PP(base + 3));
            unsigned u2 = pk2bf(PP(base + 4), PP(base + 5));
            unsigned u3 = pk2bf(PP(base + 6), PP(base + 7));
            unsigned x0 = hi ? u0 : u2;     // what partner needs
            unsigned x1 = hi ? u1 : u3;
            unsigned y0 = (unsigned)__shfl_xor((int)x0, 32);
            unsigned y1 = (unsigned)__shfl_xor((int)x1, 32);
            union { unsigned u[4]; bf16x8 v; } asm_;
            asm_.u[0] = hi ? y0 : u0;
            asm_.u[1] = hi ? y1 : u1;
            asm_.u[2] = hi ? u2 : y0;
            asm_.u[3] = hi ? u3 : y1;
            pa[ks] = asm_.v;
        }
#undef PP

        // ---- write next tile to other buffer (loads drained by compiler vmcnt) ----
        if (pre) {
            *reinterpret_cast<bf16x8*>(&Ks[cur ^ 1][SWZ(c0 >> 3, (c0 & 7) * 16)]) = sk0;
            *reinterpret_cast<bf16x8*>(&Ks[cur ^ 1][SWZ(c1 >> 3, (c1 & 7) * 16)]) = sk1;
            *reinterpret_cast<bf16x8*>(&Vs[cur ^ 1][SWZ(c0 >> 3, (c0 & 7) * 16)]) = sv0;
            *reinterpret_cast<bf16x8*>(&Vs[cur ^ 1][SWZ(c1 >> 3, (c1 & 7) * 16)]) = sv1;
        }

        // ---- PV: O^T[d,q] += V^T x P^T ----
#pragma unroll
        for (int dt = 0; dt < 2; ++dt) {
            int row = dt * 32 + l31;
#pragma unroll
            for (int ks = 0; ks < 4; ++ks) {
                bf16x8 vf = *reinterpret_cast<const bf16x8*>(&Vs[cur][SWZ(row, ks * 32 + hi * 16)]);
                oacc[dt] = __builtin_amdgcn_mfma_f32_32x32x16_bf16(vf, pa[ks], oacc[dt], 0, 0, 0);
            }
        }

        __syncthreads();
        cur ^= 1;
    }

    // ---- normalize + write [b][t][h*64+d] bf16; O rows d = crow(r,hi) ----
    float rln = 1.f / lsum;
    const size_t orow = ((size_t)b * TQ + (size_t)qt * 128 + w * 32 + l31) * DM + h * 64;
#pragma unroll
    for (int dt = 0; dt < 2; ++dt)
#pragma unroll
        for (int rq = 0; rq < 4; ++rq) {
            short4v st;
            st.x = f2bf(oacc[dt][rq * 4 + 0] * rln);
            st.y = f2bf(oacc[dt][rq * 4 + 1] * rln);
            st.z = f2bf(oacc[dt][rq * 4 + 2] * rln);
            st.w = f2bf(oacc[dt][rq * 4 + 3] * rln);
            *reinterpret_cast<short4v*>(&outA[orow + dt * 32 + rq * 8 + hi * 4]) = st;
        }
#undef SWZ
#undef KGLB
#undef VGLB
}

// ---------------------------------------------------------------------------
extern "C" void kernel_launch(void* const* d_in, const int* in_sizes, int n_in,
                              void* d_out, int out_size, void* d_ws, size_t ws_size,
                              hipStream_t stream) {
    const float* query = (const float*)d_in[0];
    const float* key_  = (const float*)d_in[1];
    const float* value = (const float*)d_in[2];
    const float* Wq = (const float*)d_in[3];
    const float* bq = (const float*)d_in[4];
    const float* Wk = (const float*)d_in[5];
    const float* bk = (const float*)d_in[6];
    const float* Wv = (const float*)d_in[7];
    const float* bv = (const float*)d_in[8];
    const float* Wo = (const float*)d_in[9];
    const float* bo = (const float*)d_in[10];
    float* out = (float*)d_out;

    char* ws = (char*)d_ws;
    float* sin_u = (float*)(ws + 0);
    float* cos_u = (float*)(ws + 524288);
    short* qh    = (short*)(ws + 1048576);
    short* kh    = (short*)(ws + 7340032);
    short* vt    = (short*)(ws + 19922944);
    short* attnO = (short*)(ws + 32505856);
    float* Y     = (float*)(ws + 38797312);

    dim3 blk(256);
    const float QSCALE = 0.125f * 1.44269504088896341f;   // fold 1/sqrt(64) * log2(e) into Q

    rope_tables<<<(TK * 32 + 255) / 256, blk, 0, stream>>>(sin_u, cos_u);

    // Q
    gemm_xwT<0><<<dim3(BQ * TQ / 128, DM / 128), blk, 0, stream>>>(query, Wq, bq, Y, BQ * TQ);
    rope_trans<<<(BQ * TQ * HEADS * 32 + 255) / 256, blk, 0, stream>>>(Y, sin_u, cos_u, qh, TQ, QSCALE);
    // K
    gemm_xwT<0><<<dim3(BQ * TK / 128, DM / 128), blk, 0, stream>>>(key_, Wk, bk, Y, BQ * TK);
    rope_trans<<<(BQ * TK * HEADS * 32 + 255) / 256, blk, 0, stream>>>(Y, sin_u, cos_u, kh, TK, 1.0f);
    // V
    gemm_xwT<0><<<dim3(BQ * TK / 128, DM / 128), blk, 0, stream>>>(value, Wv, bv, Y, BQ * TK);
    v_trans<<<dim3(TK / 64, HEADS, BQ), blk, 0, stream>>>(Y, vt);
    // attention (4 waves x 32 q-rows = 128 q-rows per block)
    attn<<<dim3(TQ / 128, HEADS, BQ), blk, 0, stream>>>(qh, kh, vt, attnO);
    // output projection (bf16 input)
    gemm_xwT<1><<<dim3(BQ * TQ / 128, DM / 128), blk, 0, stream>>>(attnO, Wo, bo, out, BQ * TQ);
}

// Round 3
// 282.890 us; speedup vs baseline: 1.4150x; 1.1064x over previous
//
#include <hip/hip_runtime.h>
#include <hip/hip_bf16.h>
#include <math.h>

#define DM 768
#define HEADS 12
#define BQ 2
#define TQ 2048
#define TK 4096
#define NSPLIT 4
#define KTS (TK / 64 / NSPLIT)          // K-tiles per split = 16
#define ROWS (BQ * HEADS * TQ)          // 49152 q-rows total

typedef __attribute__((ext_vector_type(8))) short bf16x8;   // 8 bf16 (4 VGPRs) MFMA frag
typedef __attribute__((ext_vector_type(4))) float f32x4;    // 16x16 MFMA accum
typedef __attribute__((ext_vector_type(16))) float f32x16;  // 32x32 MFMA accum
typedef __attribute__((ext_vector_type(4))) short short4v;  // 8B vector

__device__ inline short f2bf(float f) {
    union { float f; unsigned u; } a; a.f = f;
    unsigned r = a.u + 0x7fff + ((a.u >> 16) & 1);  // RNE
    return (short)(r >> 16);
}

__device__ inline float bf2f(short s) {
    union { unsigned u; float f; } a; a.u = ((unsigned)(unsigned short)s) << 16;
    return a.f;
}

// packed 2x f32 -> 1x u32 (2 bf16, lo = first arg); compiles to v_cvt_pk_bf16_f32
__device__ inline unsigned pk2bf(float a, float b) {
    union { __hip_bfloat162 h; unsigned u; } c;
    c.h = __float22bfloat162_rn(make_float2(a, b));
    return c.u;
}

// ---------------------------------------------------------------------------
// RoPE tables (fp64, matches np float64 ref). See R0 derivation.
// ---------------------------------------------------------------------------
__global__ void rope_tables(float* sin_u, float* cos_u) {
    int idx = blockIdx.x * 256 + threadIdx.x;
    if (idx >= TK * 32) return;
    int t = idx >> 5, j = idx & 31;
    double su, cu;
    if (j < 16) {
        su = sin((double)t * pow(10000.0, -(double)(2 * (2 * j)) / 64.0));
        cu = sin((double)t * pow(10000.0, -(double)(2 * (2 * j + 1)) / 64.0));
    } else {
        su = cos((double)t * pow(10000.0, -(double)(2 * (2 * j - 32)) / 64.0));
        cu = cos((double)t * pow(10000.0, -(double)(2 * (2 * j - 31)) / 64.0));
    }
    sin_u[idx] = (float)su;
    cos_u[idx] = (float)cu;
}

// ---------------------------------------------------------------------------
// GEMM: Y[M x 768] = X[M x 768] @ W^T + bias (fp32 out). Unchanged from R0.
// ---------------------------------------------------------------------------
template<int BF16IN>
__global__ __launch_bounds__(256) void gemm_xwT(const void* Xv, const float* W,
                                                const float* bias, float* Y, int M) {
    __shared__ short Alds[128 * 40];
    __shared__ short Blds[128 * 40];
    const int tid = threadIdx.x;
    const int lane = tid & 63, wid = tid >> 6;
    const int wr = wid >> 1, wc = wid & 1;
    const int l4 = lane >> 4, l15 = lane & 15;
    const int bm = blockIdx.x * 128, bn = blockIdx.y * 128;
    const float* Xf = (const float*)Xv;
    const short* Xh = (const short*)Xv;

    f32x4 acc[4][4] = {};

    for (int k0 = 0; k0 < DM; k0 += 32) {
        __syncthreads();
#pragma unroll
        for (int p = 0; p < 4; ++p) {
            int c = p * 256 + tid;
            int row = c >> 3, kq = (c & 7) * 4;
            short4v s;
            if (BF16IN) {
                s = *reinterpret_cast<const short4v*>(&Xh[(size_t)(bm + row) * DM + k0 + kq]);
            } else {
                float4 f = *reinterpret_cast<const float4*>(&Xf[(size_t)(bm + row) * DM + k0 + kq]);
                s.x = f2bf(f.x); s.y = f2bf(f.y); s.z = f2bf(f.z); s.w = f2bf(f.w);
            }
            *reinterpret_cast<short4v*>(&Alds[row * 40 + kq]) = s;
            float4 g = *reinterpret_cast<const float4*>(&W[(size_t)(bn + row) * DM + k0 + kq]);
            short4v t4;
            t4.x = f2bf(g.x); t4.y = f2bf(g.y); t4.z = f2bf(g.z); t4.w = f2bf(g.w);
            *reinterpret_cast<short4v*>(&Blds[row * 40 + kq]) = t4;
        }
        __syncthreads();
        bf16x8 af[4], bfr[4];
#pragma unroll
        for (int i = 0; i < 4; ++i)
            af[i] = *reinterpret_cast<const bf16x8*>(&Alds[(wr * 64 + i * 16 + l15) * 40 + l4 * 8]);
#pragma unroll
        for (int j = 0; j < 4; ++j)
            bfr[j] = *reinterpret_cast<const bf16x8*>(&Blds[(wc * 64 + j * 16 + l15) * 40 + l4 * 8]);
#pragma unroll
        for (int i = 0; i < 4; ++i)
#pragma unroll
            for (int j = 0; j < 4; ++j)
                acc[i][j] = __builtin_amdgcn_mfma_f32_16x16x32_bf16(af[i], bfr[j], acc[i][j], 0, 0, 0);
    }

#pragma unroll
    for (int i = 0; i < 4; ++i) {
        int m = bm + wr * 64 + i * 16 + l4 * 4;
#pragma unroll
        for (int j = 0; j < 4; ++j) {
            int n = bn + wc * 64 + j * 16 + l15;
            float bb = bias[n];
#pragma unroll
            for (int r = 0; r < 4; ++r)
                Y[(size_t)(m + r) * DM + n] = acc[i][j][r] + bb;
        }
    }
}

// ---------------------------------------------------------------------------
// RoPE + transpose to head-major bf16, with output scale (Q gets 0.125*log2e
// folded in so attention softmax runs in exp2 domain; K gets 1.0).
// ---------------------------------------------------------------------------
__global__ void rope_trans(const float* __restrict__ Y, const float* __restrict__ sin_u,
                           const float* __restrict__ cos_u, short* __restrict__ outHT,
                           int T, float scale) {
    int idx = blockIdx.x * 256 + threadIdx.x;
    if (idx >= BQ * T * HEADS * 32) return;
    int j = idx & 31;
    int tmp = idx >> 5;
    int h = tmp % HEADS;
    int row = tmp / HEADS;          // b*T + t
    int b = row / T, t = row - b * T;
    float2 x = *reinterpret_cast<const float2*>(&Y[(size_t)row * DM + h * 64 + 2 * j]);
    float su = sin_u[t * 32 + j], cu = cos_u[t * 32 + j];
    size_t base = ((size_t)(b * HEADS + h) * T + t) * 64;
    outHT[base + j]      = f2bf((x.x * cu - x.y * su) * scale);
    outHT[base + 32 + j] = f2bf((x.x * su + x.y * cu) * scale);
}

// ---------------------------------------------------------------------------
// V transpose: Y[b*TK+t][h*64+d] -> vt[(b*H+h)*64+d][t]  (bf16). Unchanged.
// ---------------------------------------------------------------------------
__global__ __launch_bounds__(256) void v_trans(const float* __restrict__ Y, short* __restrict__ vt) {
    __shared__ float tile[64][65];
    int tb = blockIdx.x, h = blockIdx.y, b = blockIdx.z;
    int tid = threadIdx.x;
#pragma unroll
    for (int p = 0; p < 4; ++p) {
        int c = p * 256 + tid;
        int tr = c >> 4, d4 = (c & 15) * 4;
        float4 f = *reinterpret_cast<const float4*>(&Y[(size_t)(b * TK + tb * 64 + tr) * DM + h * 64 + d4]);
        tile[tr][d4] = f.x; tile[tr][d4 + 1] = f.y; tile[tr][d4 + 2] = f.z; tile[tr][d4 + 3] = f.w;
    }
    __syncthreads();
#pragma unroll
    for (int p = 0; p < 4; ++p) {
        int c = p * 256 + tid;
        int d = c >> 4, t4 = (c & 15) * 4;
        short4v s;
        s.x = f2bf(tile[t4 + 0][d]); s.y = f2bf(tile[t4 + 1][d]);
        s.z = f2bf(tile[t4 + 2][d]); s.w = f2bf(tile[t4 + 3][d]);
        *reinterpret_cast<short4v*>(&vt[((size_t)(b * HEADS + h) * 64 + d) * TK + tb * 64 + t4]) = s;
    }
}

// ---------------------------------------------------------------------------
// Flash attention, swapped-operand structure + SPLIT-K over keys (NSPLIT=4).
// Block = 4 waves x 32 q-rows = 128 q-rows, keys [split*1024, split*1024+1024).
// Writes lsum-normalized partial O (bf16) + per-row {m,lsum} (f32); a combine
// kernel merges the splits exactly (log-sum-exp weights).
// Grid 16x12x8 = 1536 blocks -> ~5 blocks/CU resident (VGPR/LDS limited).
// ---------------------------------------------------------------------------
__global__ __launch_bounds__(256) void attn(const short* __restrict__ qh,
                                            const short* __restrict__ kh,
                                            const short* __restrict__ vt,
                                            short* __restrict__ Opart,
                                            float2* __restrict__ ml) {
    __shared__ short Ks[2][64 * 64];
    __shared__ short Vs[2][64 * 64];
    const int qt = blockIdx.x, h = blockIdx.y;
    const int b = blockIdx.z / NSPLIT, split = blockIdx.z % NSPLIT;
    const int tid = threadIdx.x, lane = tid & 63, w = tid >> 6;
    const int l31 = lane & 31, hi = lane >> 5;
    const size_t bh = (size_t)(b * HEADS + h);
    const short* kbase = kh + bh * TK * 64;
    const short* vbase = vt + bh * (size_t)64 * TK;
    const int t0 = split * KTS;         // first global K-tile of this split

    // swizzled LDS short-index for (row, byte-offset-within-128B-row)
#define SWZ(row, bo) ((row) * 64 + ((((bo)) ^ (((row) & 7) << 4)) >> 1))
#define KGLB(c, t_) (kbase + ((size_t)(t_) * 64 + ((c) >> 3)) * 64 + ((c) & 7) * 8)
#define VGLB(c, t_) (vbase + (size_t)((c) >> 3) * TK + (t_) * 64 + ((c) & 7) * 8)

    // Q fragments in registers (pre-scaled by 0.125*log2e)
    bf16x8 qf[4];
    {
        const short* qrow = qh + (bh * TQ + (size_t)qt * 128 + w * 32 + l31) * 64 + hi * 8;
#pragma unroll
        for (int d0 = 0; d0 < 4; ++d0)
            qf[d0] = *reinterpret_cast<const bf16x8*>(qrow + d0 * 16);
    }

    f32x16 oacc[2] = {};
    float m = -INFINITY, lsum = 0.f;

    const int c0 = tid, c1 = tid + 256;   // 2x 16B chunks each for K and V

    // prologue: stage first tile of this split
    {
        bf16x8 k0 = *reinterpret_cast<const bf16x8*>(KGLB(c0, t0));
        bf16x8 k1 = *reinterpret_cast<const bf16x8*>(KGLB(c1, t0));
        bf16x8 v0 = *reinterpret_cast<const bf16x8*>(VGLB(c0, t0));
        bf16x8 v1 = *reinterpret_cast<const bf16x8*>(VGLB(c1, t0));
        *reinterpret_cast<bf16x8*>(&Ks[0][SWZ(c0 >> 3, (c0 & 7) * 16)]) = k0;
        *reinterpret_cast<bf16x8*>(&Ks[0][SWZ(c1 >> 3, (c1 & 7) * 16)]) = k1;
        *reinterpret_cast<bf16x8*>(&Vs[0][SWZ(c0 >> 3, (c0 & 7) * 16)]) = v0;
        *reinterpret_cast<bf16x8*>(&Vs[0][SWZ(c1 >> 3, (c1 & 7) * 16)]) = v1;
    }
    __syncthreads();

    int cur = 0;
    for (int kt = 0; kt < KTS; ++kt) {
        const bool pre = (kt + 1 < KTS);
        bf16x8 sk0, sk1, sv0, sv1;
        if (pre) {   // issue next-tile loads early; latency hides under QK^T+softmax
            sk0 = *reinterpret_cast<const bf16x8*>(KGLB(c0, t0 + kt + 1));
            sk1 = *reinterpret_cast<const bf16x8*>(KGLB(c1, t0 + kt + 1));
            sv0 = *reinterpret_cast<const bf16x8*>(VGLB(c0, t0 + kt + 1));
            sv1 = *reinterpret_cast<const bf16x8*>(VGLB(c1, t0 + kt + 1));
        }

        // ---- QK^T ----
        f32x16 sacc[2] = {};
        __builtin_amdgcn_s_setprio(1);
#pragma unroll
        for (int t2 = 0; t2 < 2; ++t2) {
            int row = t2 * 32 + l31;
#pragma unroll
            for (int d0 = 0; d0 < 4; ++d0) {
                bf16x8 kf = *reinterpret_cast<const bf16x8*>(&Ks[cur][SWZ(row, d0 * 32 + hi * 16)]);
                sacc[t2] = __builtin_amdgcn_mfma_f32_32x32x16_bf16(kf, qf[d0], sacc[t2], 0, 0, 0);
            }
        }
        __builtin_amdgcn_s_setprio(0);

        // ---- online softmax (exp2 domain), per-lane row q = l31 ----
        float pmax = sacc[0][0];
#pragma unroll
        for (int i = 1; i < 16; ++i) pmax = fmaxf(pmax, sacc[0][i]);
#pragma unroll
        for (int i = 0; i < 16; ++i) pmax = fmaxf(pmax, sacc[1][i]);
        pmax = fmaxf(pmax, __shfl_xor(pmax, 32));
        if (!__all(pmax <= m + 8.f)) {      // T13 defer-max
            float mnew = fmaxf(m, pmax);
            float alpha = exp2f(m - mnew);
            lsum *= alpha;
#pragma unroll
            for (int t2 = 0; t2 < 2; ++t2)
#pragma unroll
                for (int i = 0; i < 16; ++i) oacc[t2][i] *= alpha;
            m = mnew;
        }
        float rs = 0.f;
#pragma unroll
        for (int t2 = 0; t2 < 2; ++t2)
#pragma unroll
            for (int i = 0; i < 16; ++i) {
                float e = exp2f(sacc[t2][i] - m);
                sacc[t2][i] = e;            // reuse sacc regs as P
                rs += e;
            }
        rs += __shfl_xor(rs, 32);
        lsum += rs;

        // ---- P -> PV fragments (cvt_pk + shfl_xor(32) redistribution) ----
#define PP(idx) (sacc[(idx) >> 4][(idx) & 15])
        bf16x8 pa[4];
#pragma unroll
        for (int ks = 0; ks < 4; ++ks) {
            const int base = (ks >> 1) * 16 + (ks & 1) * 8;
            unsigned u0 = pk2bf(PP(base + 0), PP(base + 1));
            unsigned u1 = pk2bf(PP(base + 2), PP(base + 3));
            unsigned u2 = pk2bf(PP(base + 4), PP(base + 5));
            unsigned u3 = pk2bf(PP(base + 6), PP(base + 7));
            unsigned x0 = hi ? u0 : u2;     // what partner needs
            unsigned x1 = hi ? u1 : u3;
            unsigned y0 = (unsigned)__shfl_xor((int)x0, 32);
            unsigned y1 = (unsigned)__shfl_xor((int)x1, 32);
            union { unsigned u[4]; bf16x8 v; } asm_;
            asm_.u[0] = hi ? y0 : u0;
            asm_.u[1] = hi ? y1 : u1;
            asm_.u[2] = hi ? u2 : y0;
            asm_.u[3] = hi ? u3 : y1;
            pa[ks] = asm_.v;
        }
#undef PP

        // ---- write next tile to other buffer (loads drained by compiler vmcnt) ----
        if (pre) {
            *reinterpret_cast<bf16x8*>(&Ks[cur ^ 1][SWZ(c0 >> 3, (c0 & 7) * 16)]) = sk0;
            *reinterpret_cast<bf16x8*>(&Ks[cur ^ 1][SWZ(c1 >> 3, (c1 & 7) * 16)]) = sk1;
            *reinterpret_cast<bf16x8*>(&Vs[cur ^ 1][SWZ(c0 >> 3, (c0 & 7) * 16)]) = sv0;
            *reinterpret_cast<bf16x8*>(&Vs[cur ^ 1][SWZ(c1 >> 3, (c1 & 7) * 16)]) = sv1;
        }

        // ---- PV: O^T[d,q] += V^T x P^T ----
        __builtin_amdgcn_s_setprio(1);
#pragma unroll
        for (int dt = 0; dt < 2; ++dt) {
            int row = dt * 32 + l31;
#pragma unroll
            for (int ks = 0; ks < 4; ++ks) {
                bf16x8 vf = *reinterpret_cast<const bf16x8*>(&Vs[cur][SWZ(row, ks * 32 + hi * 16)]);
                oacc[dt] = __builtin_amdgcn_mfma_f32_32x32x16_bf16(vf, pa[ks], oacc[dt], 0, 0, 0);
            }
        }
        __builtin_amdgcn_s_setprio(0);

        __syncthreads();
        cur ^= 1;
    }

    // ---- write lsum-normalized partial O (bf16) + {m, lsum} ----
    float rln = 1.f / lsum;
    const size_t R = bh * TQ + (size_t)qt * 128 + w * 32 + l31;
    const size_t obase = ((size_t)split * ROWS + R) * 64;
#pragma unroll
    for (int dt = 0; dt < 2; ++dt)
#pragma unroll
        for (int rq = 0; rq < 4; ++rq) {
            short4v st;
            st.x = f2bf(oacc[dt][rq * 4 + 0] * rln);
            st.y = f2bf(oacc[dt][rq * 4 + 1] * rln);
            st.z = f2bf(oacc[dt][rq * 4 + 2] * rln);
            st.w = f2bf(oacc[dt][rq * 4 + 3] * rln);
            *reinterpret_cast<short4v*>(&Opart[obase + dt * 32 + rq * 8 + hi * 4]) = st;
        }
    if (hi == 0)
        ml[(size_t)split * ROWS + R] = make_float2(m, lsum);
#undef SWZ
#undef KGLB
#undef VGLB
}

// ---------------------------------------------------------------------------
// Combine NSPLIT partials: exact log-sum-exp merge.
// thread = (row R, d-group g of 8). attnO layout [b][t][h*64+d] (token-major).
// ---------------------------------------------------------------------------
__global__ __launch_bounds__(256) void attn_combine(const short* __restrict__ Opart,
                                                    const float2* __restrict__ ml,
                                                    short* __restrict__ attnO) {
    int idx = blockIdx.x * 256 + threadIdx.x;
    int R = idx >> 3, g = idx & 7;
    float2 mls[NSPLIT];
    float m0 = -INFINITY;
#pragma unroll
    for (int s = 0; s < NSPLIT; ++s) {
        mls[s] = ml[(size_t)s * ROWS + R];
        m0 = fmaxf(m0, mls[s].x);
    }
    float wgt[NSPLIT], L = 0.f;
#pragma unroll
    for (int s = 0; s < NSPLIT; ++s) {
        wgt[s] = mls[s].y * exp2f(mls[s].x - m0);
        L += wgt[s];
    }
    float rL = 1.f / L;
    float o[8] = {};
#pragma unroll
    for (int s = 0; s < NSPLIT; ++s) {
        float c = wgt[s] * rL;
        bf16x8 v = *reinterpret_cast<const bf16x8*>(&Opart[(((size_t)s * ROWS + R) * 64) + g * 8]);
#pragma unroll
        for (int i = 0; i < 8; ++i) o[i] += c * bf2f(v[i]);
    }
    int bh = R >> 11, t = R & 2047;
    int b = bh / HEADS, h = bh - b * HEADS;
    short4v s0, s1;
    s0.x = f2bf(o[0]); s0.y = f2bf(o[1]); s0.z = f2bf(o[2]); s0.w = f2bf(o[3]);
    s1.x = f2bf(o[4]); s1.y = f2bf(o[5]); s1.z = f2bf(o[6]); s1.w = f2bf(o[7]);
    size_t dst = (((size_t)b * TQ + t) * HEADS + h) * 64 + g * 8;
    *reinterpret_cast<short4v*>(&attnO[dst]) = s0;
    *reinterpret_cast<short4v*>(&attnO[dst + 4]) = s1;
}

// ---------------------------------------------------------------------------
extern "C" void kernel_launch(void* const* d_in, const int* in_sizes, int n_in,
                              void* d_out, int out_size, void* d_ws, size_t ws_size,
                              hipStream_t stream) {
    const float* query = (const float*)d_in[0];
    const float* key_  = (const float*)d_in[1];
    const float* value = (const float*)d_in[2];
    const float* Wq = (const float*)d_in[3];
    const float* bq = (const float*)d_in[4];
    const float* Wk = (const float*)d_in[5];
    const float* bk = (const float*)d_in[6];
    const float* Wv = (const float*)d_in[7];
    const float* bv = (const float*)d_in[8];
    const float* Wo = (const float*)d_in[9];
    const float* bo = (const float*)d_in[10];
    float* out = (float*)d_out;

    char* ws = (char*)d_ws;
    float* sin_u = (float*)(ws + 0);            //   524,288 B
    float* cos_u = (float*)(ws + 524288);       //   524,288 B
    short* qh    = (short*)(ws + 1048576);      // 6,291,456 B
    short* kh    = (short*)(ws + 7340032);      // 12,582,912 B
    short* vt    = (short*)(ws + 19922944);     // 12,582,912 B
    short* attnO = (short*)(ws + 32505856);     // 6,291,456 B
    float* Y     = (float*)(ws + 38797312);     // 25,165,824 B (dead after v_trans)
    short* Opart = (short*)(ws + 38797312);     // aliases Y: 4*49152*64*2 = 25,165,824 B
    float2* ml   = (float2*)(ws + 63963136);    // 1,572,864 B (end ~65.5 MB)

    dim3 blk(256);
    const float QSCALE = 0.125f * 1.44269504088896341f;   // fold 1/sqrt(64) * log2(e) into Q

    rope_tables<<<(TK * 32 + 255) / 256, blk, 0, stream>>>(sin_u, cos_u);

    // Q
    gemm_xwT<0><<<dim3(BQ * TQ / 128, DM / 128), blk, 0, stream>>>(query, Wq, bq, Y, BQ * TQ);
    rope_trans<<<(BQ * TQ * HEADS * 32 + 255) / 256, blk, 0, stream>>>(Y, sin_u, cos_u, qh, TQ, QSCALE);
    // K
    gemm_xwT<0><<<dim3(BQ * TK / 128, DM / 128), blk, 0, stream>>>(key_, Wk, bk, Y, BQ * TK);
    rope_trans<<<(BQ * TK * HEADS * 32 + 255) / 256, blk, 0, stream>>>(Y, sin_u, cos_u, kh, TK, 1.0f);
    // V
    gemm_xwT<0><<<dim3(BQ * TK / 128, DM / 128), blk, 0, stream>>>(value, Wv, bv, Y, BQ * TK);
    v_trans<<<dim3(TK / 64, HEADS, BQ), blk, 0, stream>>>(Y, vt);
    // attention, split-K over keys (Opart aliases Y — Y is dead by here)
    attn<<<dim3(TQ / 128, HEADS, BQ * NSPLIT), blk, 0, stream>>>(qh, kh, vt, Opart, ml);
    attn_combine<<<ROWS * 8 / 256, blk, 0, stream>>>(Opart, ml, attnO);
    // output projection (bf16 input)
    gemm_xwT<1><<<dim3(BQ * TQ / 128, DM / 128), blk, 0, stream>>>(attnO, Wo, bo, out, BQ * TQ);
}

// Round 5
// 272.510 us; speedup vs baseline: 1.4689x; 1.0381x over previous
//
#include <hip/hip_runtime.h>
#include <hip/hip_bf16.h>
#include <math.h>

#define DM 768
#define HEADS 12
#define BQ 2
#define TQ 2048
#define TK 4096
#define NSPLIT 4
#define KTS (TK / 64 / NSPLIT)          // K-tiles per split = 16
#define ROWS (BQ * HEADS * TQ)          // 49152 q-rows total

typedef __attribute__((ext_vector_type(8))) short bf16x8;   // 8 bf16 (4 VGPRs) MFMA frag
typedef __attribute__((ext_vector_type(4))) float f32x4;    // 16x16 MFMA accum
typedef __attribute__((ext_vector_type(16))) float f32x16;  // 32x32 MFMA accum
typedef __attribute__((ext_vector_type(4))) short short4v;  // 8B vector
typedef __attribute__((ext_vector_type(2))) unsigned uint2v; // 8B vector

__device__ inline short f2bf(float f) {
    union { float f; unsigned u; } a; a.f = f;
    unsigned r = a.u + 0x7fff + ((a.u >> 16) & 1);  // RNE
    return (short)(r >> 16);
}

__device__ inline float bf2f(short s) {
    union { unsigned u; float f; } a; a.u = ((unsigned)(unsigned short)s) << 16;
    return a.f;
}

// packed 2x f32 -> 1x u32 (2 bf16, lo = first arg); v_cvt_pk_bf16_f32
__device__ inline unsigned pk2bf(float a, float b) {
    union { __hip_bfloat162 h; unsigned u; } c;
    c.h = __float22bfloat162_rn(make_float2(a, b));
    return c.u;
}

// v_permlane32_swap_b32 via the OFFICIAL builtin (compiler handles the
// VALU->permlane hazard wait-states; R4's inline-asm version read stale regs).
// Returns: a' = {a[0:31], b[0:31]}, b' = {a[32:63], b[32:63]}.
__device__ inline void plswap(unsigned &a, unsigned &b) {
    uint2v r = __builtin_amdgcn_permlane32_swap(a, b, false, false);
    a = r[0]; b = r[1];
}
// cross-half exchange of x: a = {x_lo, x_lo}, b = {x_hi, x_hi}
__device__ inline void plswap2(unsigned &a, unsigned &b, unsigned x) {
    uint2v r = __builtin_amdgcn_permlane32_swap(x, x, false, false);
    a = r[0]; b = r[1];
}
__device__ inline float max3f(float a, float b, float c) { return fmaxf(fmaxf(a, b), c); }

// ---------------------------------------------------------------------------
// RoPE tables (fp64, matches np float64 ref). See R0 derivation.
// ---------------------------------------------------------------------------
__global__ void rope_tables(float* sin_u, float* cos_u) {
    int idx = blockIdx.x * 256 + threadIdx.x;
    if (idx >= TK * 32) return;
    int t = idx >> 5, j = idx & 31;
    double su, cu;
    if (j < 16) {
        su = sin((double)t * pow(10000.0, -(double)(2 * (2 * j)) / 64.0));
        cu = sin((double)t * pow(10000.0, -(double)(2 * (2 * j + 1)) / 64.0));
    } else {
        su = cos((double)t * pow(10000.0, -(double)(2 * (2 * j - 32)) / 64.0));
        cu = cos((double)t * pow(10000.0, -(double)(2 * (2 * j - 31)) / 64.0));
    }
    sin_u[idx] = (float)su;
    cos_u[idx] = (float)cu;
}

// ---------------------------------------------------------------------------
// GEMM: Y[M x 768] = X[M x 768] @ W^T + bias (fp32 out).
// Staging uses v_cvt_pk_bf16_f32 (2 elems/instr) instead of manual RNE.
// ---------------------------------------------------------------------------
template<int BF16IN>
__global__ __launch_bounds__(256) void gemm_xwT(const void* Xv, const float* W,
                                                const float* bias, float* Y, int M) {
    __shared__ short Alds[128 * 40];
    __shared__ short Blds[128 * 40];
    const int tid = threadIdx.x;
    const int lane = tid & 63, wid = tid >> 6;
    const int wr = wid >> 1, wc = wid & 1;
    const int l4 = lane >> 4, l15 = lane & 15;
    const int bm = blockIdx.x * 128, bn = blockIdx.y * 128;
    const float* Xf = (const float*)Xv;
    const short* Xh = (const short*)Xv;

    f32x4 acc[4][4] = {};

    for (int k0 = 0; k0 < DM; k0 += 32) {
        __syncthreads();
#pragma unroll
        for (int p = 0; p < 4; ++p) {
            int c = p * 256 + tid;
            int row = c >> 3, kq = (c & 7) * 4;
            if (BF16IN) {
                *reinterpret_cast<short4v*>(&Alds[row * 40 + kq]) =
                    *reinterpret_cast<const short4v*>(&Xh[(size_t)(bm + row) * DM + k0 + kq]);
            } else {
                float4 f = *reinterpret_cast<const float4*>(&Xf[(size_t)(bm + row) * DM + k0 + kq]);
                uint2v s; s.x = pk2bf(f.x, f.y); s.y = pk2bf(f.z, f.w);
                *reinterpret_cast<uint2v*>(&Alds[row * 40 + kq]) = s;
            }
            float4 g = *reinterpret_cast<const float4*>(&W[(size_t)(bn + row) * DM + k0 + kq]);
            uint2v t4; t4.x = pk2bf(g.x, g.y); t4.y = pk2bf(g.z, g.w);
            *reinterpret_cast<uint2v*>(&Blds[row * 40 + kq]) = t4;
        }
        __syncthreads();
        bf16x8 af[4], bfr[4];
#pragma unroll
        for (int i = 0; i < 4; ++i)
            af[i] = *reinterpret_cast<const bf16x8*>(&Alds[(wr * 64 + i * 16 + l15) * 40 + l4 * 8]);
#pragma unroll
        for (int j = 0; j < 4; ++j)
            bfr[j] = *reinterpret_cast<const bf16x8*>(&Blds[(wc * 64 + j * 16 + l15) * 40 + l4 * 8]);
#pragma unroll
        for (int i = 0; i < 4; ++i)
#pragma unroll
            for (int j = 0; j < 4; ++j)
                acc[i][j] = __builtin_amdgcn_mfma_f32_16x16x32_bf16(af[i], bfr[j], acc[i][j], 0, 0, 0);
    }

#pragma unroll
    for (int i = 0; i < 4; ++i) {
        int m = bm + wr * 64 + i * 16 + l4 * 4;
#pragma unroll
        for (int j = 0; j < 4; ++j) {
            int n = bn + wc * 64 + j * 16 + l15;
            float bb = bias[n];
#pragma unroll
            for (int r = 0; r < 4; ++r)
                Y[(size_t)(m + r) * DM + n] = acc[i][j][r] + bb;
        }
    }
}

// ---------------------------------------------------------------------------
// RoPE + transpose to head-major bf16, with output scale (Q gets 0.125*log2e
// folded in so attention softmax runs in exp2 domain; K gets 1.0).
// ---------------------------------------------------------------------------
__global__ void rope_trans(const float* __restrict__ Y, const float* __restrict__ sin_u,
                           const float* __restrict__ cos_u, short* __restrict__ outHT,
                           int T, float scale) {
    int idx = blockIdx.x * 256 + threadIdx.x;
    if (idx >= BQ * T * HEADS * 32) return;
    int j = idx & 31;
    int tmp = idx >> 5;
    int h = tmp % HEADS;
    int row = tmp / HEADS;          // b*T + t
    int b = row / T, t = row - b * T;
    float2 x = *reinterpret_cast<const float2*>(&Y[(size_t)row * DM + h * 64 + 2 * j]);
    float su = sin_u[t * 32 + j], cu = cos_u[t * 32 + j];
    size_t base = ((size_t)(b * HEADS + h) * T + t) * 64;
    outHT[base + j]      = f2bf((x.x * cu - x.y * su) * scale);
    outHT[base + 32 + j] = f2bf((x.x * su + x.y * cu) * scale);
}

// ---------------------------------------------------------------------------
// V transpose: Y[b*TK+t][h*64+d] -> vt[(b*H+h)*64+d][t]  (bf16).
// ---------------------------------------------------------------------------
__global__ __launch_bounds__(256) void v_trans(const float* __restrict__ Y, short* __restrict__ vt) {
    __shared__ float tile[64][65];
    int tb = blockIdx.x, h = blockIdx.y, b = blockIdx.z;
    int tid = threadIdx.x;
#pragma unroll
    for (int p = 0; p < 4; ++p) {
        int c = p * 256 + tid;
        int tr = c >> 4, d4 = (c & 15) * 4;
        float4 f = *reinterpret_cast<const float4*>(&Y[(size_t)(b * TK + tb * 64 + tr) * DM + h * 64 + d4]);
        tile[tr][d4] = f.x; tile[tr][d4 + 1] = f.y; tile[tr][d4 + 2] = f.z; tile[tr][d4 + 3] = f.w;
    }
    __syncthreads();
#pragma unroll
    for (int p = 0; p < 4; ++p) {
        int c = p * 256 + tid;
        int d = c >> 4, t4 = (c & 15) * 4;
        uint2v s;
        s.x = pk2bf(tile[t4 + 0][d], tile[t4 + 1][d]);
        s.y = pk2bf(tile[t4 + 2][d], tile[t4 + 3][d]);
        *reinterpret_cast<uint2v*>(&vt[((size_t)(b * HEADS + h) * 64 + d) * TK + tb * 64 + t4]) = s;
    }
}

// ---------------------------------------------------------------------------
// Flash attention, swapped-operand + split-K (NSPLIT=4).
// permlane32_swap (builtin) for all cross-half exchanges; max3 tree; tree sum;
// hoisted swizzled LDS offsets; launch_bounds(256,4).
// ---------------------------------------------------------------------------
__global__ __launch_bounds__(256, 4) void attn(const short* __restrict__ qh,
                                               const short* __restrict__ kh,
                                               const short* __restrict__ vt,
                                               short* __restrict__ Opart,
                                               float2* __restrict__ ml) {
    __shared__ short Ks[2][64 * 64];
    __shared__ short Vs[2][64 * 64];
    const int qt = blockIdx.x, h = blockIdx.y;
    const int b = blockIdx.z / NSPLIT, split = blockIdx.z % NSPLIT;
    const int tid = threadIdx.x, lane = tid & 63, w = tid >> 6;
    const int l31 = lane & 31, hi = lane >> 5;
    const size_t bh = (size_t)(b * HEADS + h);
    const short* kbase = kh + bh * TK * 64;
    const short* vbase = vt + bh * (size_t)64 * TK;
    const int t0 = split * KTS;

#define SWZ(row, bo) ((row) * 64 + ((((bo)) ^ (((row) & 7) << 4)) >> 1))
#define KGLB(c, t_) (kbase + ((size_t)(t_) * 64 + ((c) >> 3)) * 64 + ((c) & 7) * 8)
#define VGLB(c, t_) (vbase + (size_t)((c) >> 3) * TK + (t_) * 64 + ((c) & 7) * 8)

    // hoisted swizzled LDS read offsets: [t2(row-half)][d0] — same for K and V
    int loff[2][4];
#pragma unroll
    for (int t2 = 0; t2 < 2; ++t2)
#pragma unroll
        for (int d0 = 0; d0 < 4; ++d0)
            loff[t2][d0] = SWZ(t2 * 32 + l31, d0 * 32 + hi * 16);

    bf16x8 qf[4];
    {
        const short* qrow = qh + (bh * TQ + (size_t)qt * 128 + w * 32 + l31) * 64 + hi * 8;
#pragma unroll
        for (int d0 = 0; d0 < 4; ++d0)
            qf[d0] = *reinterpret_cast<const bf16x8*>(qrow + d0 * 16);
    }

    f32x16 oacc[2] = {};
    float m = -INFINITY, lsum = 0.f;

    const int c0 = tid, c1 = tid + 256;
    const int sw0 = SWZ(c0 >> 3, (c0 & 7) * 16), sw1 = SWZ(c1 >> 3, (c1 & 7) * 16);

    {   // prologue: stage first tile of this split
        bf16x8 k0 = *reinterpret_cast<const bf16x8*>(KGLB(c0, t0));
        bf16x8 k1 = *reinterpret_cast<const bf16x8*>(KGLB(c1, t0));
        bf16x8 v0 = *reinterpret_cast<const bf16x8*>(VGLB(c0, t0));
        bf16x8 v1 = *reinterpret_cast<const bf16x8*>(VGLB(c1, t0));
        *reinterpret_cast<bf16x8*>(&Ks[0][sw0]) = k0;
        *reinterpret_cast<bf16x8*>(&Ks[0][sw1]) = k1;
        *reinterpret_cast<bf16x8*>(&Vs[0][sw0]) = v0;
        *reinterpret_cast<bf16x8*>(&Vs[0][sw1]) = v1;
    }
    __syncthreads();

    int cur = 0;
    for (int kt = 0; kt < KTS; ++kt) {
        const bool pre = (kt + 1 < KTS);
        bf16x8 sk0, sk1, sv0, sv1;
        if (pre) {
            sk0 = *reinterpret_cast<const bf16x8*>(KGLB(c0, t0 + kt + 1));
            sk1 = *reinterpret_cast<const bf16x8*>(KGLB(c1, t0 + kt + 1));
            sv0 = *reinterpret_cast<const bf16x8*>(VGLB(c0, t0 + kt + 1));
            sv1 = *reinterpret_cast<const bf16x8*>(VGLB(c1, t0 + kt + 1));
        }

        // ---- QK^T ----
        f32x16 sacc[2] = {};
        __builtin_amdgcn_s_setprio(1);
#pragma unroll
        for (int t2 = 0; t2 < 2; ++t2)
#pragma unroll
            for (int d0 = 0; d0 < 4; ++d0) {
                bf16x8 kf = *reinterpret_cast<const bf16x8*>(&Ks[cur][loff[t2][d0]]);
                sacc[t2] = __builtin_amdgcn_mfma_f32_32x32x16_bf16(kf, qf[d0], sacc[t2], 0, 0, 0);
            }
        __builtin_amdgcn_s_setprio(0);

        // ---- row max: pairwise + max3 tree, then cross-half via permlane ----
        float t16[16];
#pragma unroll
        for (int i = 0; i < 16; ++i) t16[i] = fmaxf(sacc[0][i], sacc[1][i]);
        float t6_0 = max3f(t16[0], t16[1], t16[2]);
        float t6_1 = max3f(t16[3], t16[4], t16[5]);
        float t6_2 = max3f(t16[6], t16[7], t16[8]);
        float t6_3 = max3f(t16[9], t16[10], t16[11]);
        float t6_4 = max3f(t16[12], t16[13], t16[14]);
        float pmax = fmaxf(max3f(t6_0, t6_1, t6_2), max3f(t6_3, t6_4, t16[15]));
        {
            unsigned a, bb2;
            plswap2(a, bb2, __float_as_uint(pmax));
            pmax = fmaxf(__uint_as_float(a), __uint_as_float(bb2));
        }
        if (!__all(pmax <= m + 8.f)) {      // T13 defer-max
            float mnew = fmaxf(m, pmax);
            float alpha = exp2f(m - mnew);
            lsum *= alpha;
#pragma unroll
            for (int t2 = 0; t2 < 2; ++t2)
#pragma unroll
                for (int i = 0; i < 16; ++i) oacc[t2][i] *= alpha;
            m = mnew;
        }

        // ---- exp + tree sum ----
#pragma unroll
        for (int t2 = 0; t2 < 2; ++t2)
#pragma unroll
            for (int i = 0; i < 16; ++i)
                sacc[t2][i] = exp2f(sacc[t2][i] - m);
        float s8[8];
#pragma unroll
        for (int i = 0; i < 8; ++i)
            s8[i] = (sacc[0][i] + sacc[0][i + 8]) + (sacc[1][i] + sacc[1][i + 8]);
        float rs = ((s8[0] + s8[1]) + (s8[2] + s8[3])) + ((s8[4] + s8[5]) + (s8[6] + s8[7]));
        {
            unsigned a, bb2;
            plswap2(a, bb2, __float_as_uint(rs));
            rs = __uint_as_float(a) + __uint_as_float(bb2);
        }
        lsum += rs;

        // ---- P -> PV fragments: cvt_pk + permlane32_swap ----
#define PP(idx) (sacc[(idx) >> 4][(idx) & 15])
        bf16x8 pa[4];
#pragma unroll
        for (int ks = 0; ks < 4; ++ks) {
            const int base = (ks >> 1) * 16 + (ks & 1) * 8;
            unsigned u0 = pk2bf(PP(base + 0), PP(base + 1));
            unsigned u1 = pk2bf(PP(base + 2), PP(base + 3));
            unsigned u2 = pk2bf(PP(base + 4), PP(base + 5));
            unsigned u3 = pk2bf(PP(base + 6), PP(base + 7));
            plswap(u0, u2);   // (u0,u2) = exchanged quads across lane^32
            plswap(u1, u3);
            union { unsigned u[4]; bf16x8 v; } asm_;
            asm_.u[0] = u0; asm_.u[1] = u1; asm_.u[2] = u2; asm_.u[3] = u3;
            pa[ks] = asm_.v;
        }
#undef PP

        // ---- write next tile to other buffer ----
        if (pre) {
            *reinterpret_cast<bf16x8*>(&Ks[cur ^ 1][sw0]) = sk0;
            *reinterpret_cast<bf16x8*>(&Ks[cur ^ 1][sw1]) = sk1;
            *reinterpret_cast<bf16x8*>(&Vs[cur ^ 1][sw0]) = sv0;
            *reinterpret_cast<bf16x8*>(&Vs[cur ^ 1][sw1]) = sv1;
        }

        // ---- PV: O^T[d,q] += V^T x P^T ----
        __builtin_amdgcn_s_setprio(1);
#pragma unroll
        for (int dt = 0; dt < 2; ++dt)
#pragma unroll
            for (int ks = 0; ks < 4; ++ks) {
                bf16x8 vf = *reinterpret_cast<const bf16x8*>(&Vs[cur][loff[dt][ks]]);
                oacc[dt] = __builtin_amdgcn_mfma_f32_32x32x16_bf16(vf, pa[ks], oacc[dt], 0, 0, 0);
            }
        __builtin_amdgcn_s_setprio(0);

        __syncthreads();
        cur ^= 1;
    }

    // ---- write lsum-normalized partial O (bf16) + {m, lsum} ----
    float rln = 1.f / lsum;
    const size_t R = bh * TQ + (size_t)qt * 128 + w * 32 + l31;
    const size_t obase = ((size_t)split * ROWS + R) * 64;
#pragma unroll
    for (int dt = 0; dt < 2; ++dt)
#pragma unroll
        for (int rq = 0; rq < 4; ++rq) {
            uint2v st;
            st.x = pk2bf(oacc[dt][rq * 4 + 0] * rln, oacc[dt][rq * 4 + 1] * rln);
            st.y = pk2bf(oacc[dt][rq * 4 + 2] * rln, oacc[dt][rq * 4 + 3] * rln);
            *reinterpret_cast<uint2v*>(&Opart[obase + dt * 32 + rq * 8 + hi * 4]) = st;
        }
    if (hi == 0)
        ml[(size_t)split * ROWS + R] = make_float2(m, lsum);
#undef SWZ
#undef KGLB
#undef VGLB
}

// ---------------------------------------------------------------------------
// Combine NSPLIT partials: exact log-sum-exp merge.
// ---------------------------------------------------------------------------
__global__ __launch_bounds__(256) void attn_combine(const short* __restrict__ Opart,
                                                    const float2* __restrict__ ml,
                                                    short* __restrict__ attnO) {
    int idx = blockIdx.x * 256 + threadIdx.x;
    int R = idx >> 3, g = idx & 7;
    float2 mls[NSPLIT];
    float m0 = -INFINITY;
#pragma unroll
    for (int s = 0; s < NSPLIT; ++s) {
        mls[s] = ml[(size_t)s * ROWS + R];
        m0 = fmaxf(m0, mls[s].x);
    }
    float wgt[NSPLIT], L = 0.f;
#pragma unroll
    for (int s = 0; s < NSPLIT; ++s) {
        wgt[s] = mls[s].y * exp2f(mls[s].x - m0);
        L += wgt[s];
    }
    float rL = 1.f / L;
    float o[8] = {};
#pragma unroll
    for (int s = 0; s < NSPLIT; ++s) {
        float c = wgt[s] * rL;
        bf16x8 v = *reinterpret_cast<const bf16x8*>(&Opart[(((size_t)s * ROWS + R) * 64) + g * 8]);
#pragma unroll
        for (int i = 0; i < 8; ++i) o[i] += c * bf2f(v[i]);
    }
    int bh = R >> 11, t = R & 2047;
    int b = bh / HEADS, h = bh - b * HEADS;
    uint2v s0, s1;
    s0.x = pk2bf(o[0], o[1]); s0.y = pk2bf(o[2], o[3]);
    s1.x = pk2bf(o[4], o[5]); s1.y = pk2bf(o[6], o[7]);
    size_t dst = (((size_t)b * TQ + t) * HEADS + h) * 64 + g * 8;
    *reinterpret_cast<uint2v*>(&attnO[dst]) = s0;
    *reinterpret_cast<uint2v*>(&attnO[dst + 4]) = s1;
}

// ---------------------------------------------------------------------------
extern "C" void kernel_launch(void* const* d_in, const int* in_sizes, int n_in,
                              void* d_out, int out_size, void* d_ws, size_t ws_size,
                              hipStream_t stream) {
    const float* query = (const float*)d_in[0];
    const float* key_  = (const float*)d_in[1];
    const float* value = (const float*)d_in[2];
    const float* Wq = (const float*)d_in[3];
    const float* bq = (const float*)d_in[4];
    const float* Wk = (const float*)d_in[5];
    const float* bk = (const float*)d_in[6];
    const float* Wv = (const float*)d_in[7];
    const float* bv = (const float*)d_in[8];
    const float* Wo = (const float*)d_in[9];
    const float* bo = (const float*)d_in[10];
    float* out = (float*)d_out;

    char* ws = (char*)d_ws;
    float* sin_u = (float*)(ws + 0);            //   524,288 B
    float* cos_u = (float*)(ws + 524288);       //   524,288 B
    short* qh    = (short*)(ws + 1048576);      // 6,291,456 B
    short* kh    = (short*)(ws + 7340032);      // 12,582,912 B
    short* vt    = (short*)(ws + 19922944);     // 12,582,912 B
    short* attnO = (short*)(ws + 32505856);     // 6,291,456 B
    float* Y     = (float*)(ws + 38797312);     // 25,165,824 B (dead after v_trans)
    short* Opart = (short*)(ws + 38797312);     // aliases Y
    float2* ml   = (float2*)(ws + 63963136);    // 1,572,864 B (end ~65.5 MB)

    dim3 blk(256);
    const float QSCALE = 0.125f * 1.44269504088896341f;

    rope_tables<<<(TK * 32 + 255) / 256, blk, 0, stream>>>(sin_u, cos_u);

    // Q
    gemm_xwT<0><<<dim3(BQ * TQ / 128, DM / 128), blk, 0, stream>>>(query, Wq, bq, Y, BQ * TQ);
    rope_trans<<<(BQ * TQ * HEADS * 32 + 255) / 256, blk, 0, stream>>>(Y, sin_u, cos_u, qh, TQ, QSCALE);
    // K
    gemm_xwT<0><<<dim3(BQ * TK / 128, DM / 128), blk, 0, stream>>>(key_, Wk, bk, Y, BQ * TK);
    rope_trans<<<(BQ * TK * HEADS * 32 + 255) / 256, blk, 0, stream>>>(Y, sin_u, cos_u, kh, TK, 1.0f);
    // V
    gemm_xwT<0><<<dim3(BQ * TK / 128, DM / 128), blk, 0, stream>>>(value, Wv, bv, Y, BQ * TK);
    v_trans<<<dim3(TK / 64, HEADS, BQ), blk, 0, stream>>>(Y, vt);
    // attention, split-K
    attn<<<dim3(TQ / 128, HEADS, BQ * NSPLIT), blk, 0, stream>>>(qh, kh, vt, Opart, ml);
    attn_combine<<<ROWS * 8 / 256, blk, 0, stream>>>(Opart, ml, attnO);
    // output projection (bf16 input)
    gemm_xwT<1><<<dim3(BQ * TQ / 128, DM / 128), blk, 0, stream>>>(attnO, Wo, bo, out, BQ * TQ);
}